// Round 1
// baseline (237.522 us; speedup 1.0000x reference)
//
#include <hip/hip_runtime.h>
#include <math.h>

#define Bn 256
#define Cn 3
#define Hn 224
#define Wn 224
#define Sn 20
#define Mn 10
#define NFEAT 5
#define NHID 100
#define NOUT 10

// K1: one thread per (s,b). Computes the mixture sample, logprob, loc, and the
// 3-channel pixel gather; writes flat samples[(s*B+b)*5+f] and logprob[s*B+b].
__global__ __launch_bounds__(256) void k_sample(
    const float* __restrict__ x, const float* __restrict__ u_cat,
    const float* __restrict__ z, const float* __restrict__ mg,
    float* __restrict__ samples, float* __restrict__ logprob)
{
    __shared__ float p[6 * Mn];
    const int b = threadIdx.x;   // batch index 0..255
    const int s = blockIdx.x;    // sample index 0..19
    if (b < 6 * Mn) p[b] = mg[b];
    __syncthreads();

    // pi row b of the reshape-scrambled (B,M) matrix: value = p0[(b*10+m)//256]
    float raw[Mn];
#pragma unroll
    for (int m = 0; m < Mn; ++m) raw[m] = p[((b * Mn + m) >> 8) * 6 + 0];
    float mx = raw[0];
#pragma unroll
    for (int m = 1; m < Mn; ++m) mx = fmaxf(mx, raw[m]);
    float e[Mn];
    float sum = 0.f;
#pragma unroll
    for (int m = 0; m < Mn; ++m) { e[m] = expf(raw[m] - mx); sum += e[m]; }

    // idx = argmax(u < cdf)  (first true; 0 if none)
    const float u = u_cat[s * Bn + b];
    float cdf = 0.f;
    int idx = 0;
    bool found = false;
#pragma unroll
    for (int m = 0; m < Mn; ++m) {
        cdf += e[m] / sum;
        if (!found && u < cdf) { idx = m; found = true; }
    }

    const int g = (b * Mn + idx) >> 8;   // param bucket
    const float mux = p[g * 6 + 1];
    const float muy = p[g * 6 + 2];
    const float sx  = expf(p[g * 6 + 3]);
    const float sy  = expf(p[g * 6 + 4]);
    const float r   = tanhf(p[g * 6 + 5]);

    const float z1 = z[(s * Bn + b) * 2 + 0];
    const float z2 = z[(s * Bn + b) * 2 + 1];

    const float px = mux + sx * z1;
    const float py = muy + sy * (r * z1 + sqrtf(1.f - r * r) * z2);
    const float zx = (px - mux) / sx;
    const float zy = (py - muy) / sy;
    const float omr2 = 1.f - r * r;
    const float lp = -(zx * zx - 2.f * r * zx * zy + zy * zy) / (2.f * omr2)
                     - logf(6.283185307179586f * sx * sy * sqrtf(omr2));

    const float lx = tanhf(px);
    const float ly = tanhf(py);

    // rows/cols: trunc(0.5*(loc+1)*H - 0.1), clipped. (ref uses H in both)
    const float vr = 0.5f * (lx + 1.f) * (float)Hn - 0.1f;
    const float vc = 0.5f * (ly + 1.f) * (float)Hn - 0.1f;
    int row = (int)vr; row = min(max(row, 0), Hn - 1);
    int col = (int)vc; col = min(max(col, 0), Wn - 1);

    const int base = (b * Cn) * (Hn * Wn) + row * Wn + col;
    const int o5 = (s * Bn + b) * NFEAT;
    samples[o5 + 0] = x[base + 0 * Hn * Wn];
    samples[o5 + 1] = x[base + 1 * Hn * Wn];
    samples[o5 + 2] = x[base + 2 * Hn * Wn];
    samples[o5 + 3] = lx;
    samples[o5 + 4] = ly;
    logprob[s * Bn + b] = lp;
}

// K2: single block of 256 threads (one per batch row). Feature sum over the
// contiguous 20x5 chunk (reshape identity: t = s*B+b = b'*20+s'), the two
// collapsed "graph convs" (adj=ones => sum over S), cross-batch log_softmax
// via shared memory, and the final collapsed FC + softmax. Also reduces
// full_log_prob.
__global__ __launch_bounds__(256) void k_head(
    const float* __restrict__ samples, const float* __restrict__ logprob,
    const float* __restrict__ w1, const float* __restrict__ b1,
    const float* __restrict__ w2, const float* __restrict__ b2,
    const float* __restrict__ wf, const float* __restrict__ bf,
    float* __restrict__ out)
{
    const int b = threadIdx.x;
    __shared__ float sh_gv[NOUT][Bn];        // 10 KiB
    __shared__ float sh_part[NOUT][16];
    __shared__ float sh_max[NOUT];
    __shared__ float sh_lse[NOUT];
    __shared__ float sh_wsum[NOUT * NOUT];   // [k*10+o]

    // output 1: full_log_prob[b] = sum_s logprob[s,b]
    float flp = 0.f;
#pragma unroll
    for (int s = 0; s < Sn; ++s) flp += logprob[s * Bn + b];
    out[Bn * NOUT + b] = flp;

    // fs[f] = sum over the 20 contiguous samples of this b'
    float fs[NFEAT] = {0.f, 0.f, 0.f, 0.f, 0.f};
    const float* sp = samples + b * Sn * NFEAT;
    for (int j = 0; j < Sn; ++j) {
#pragma unroll
        for (int f = 0; f < NFEAT; ++f) fs[f] += sp[j * NFEAT + f];
    }

    // gv[k] = S * (relu(fs.W1 + b1) . W2)[k] + b2[k]
    float gv[NOUT];
#pragma unroll
    for (int k = 0; k < NOUT; ++k) gv[k] = 0.f;
    for (int j = 0; j < NHID; ++j) {
        float a = b1[j];
#pragma unroll
        for (int f = 0; f < NFEAT; ++f) a += fs[f] * w1[f * NHID + j];
        const float h = fmaxf(a, 0.f);
#pragma unroll
        for (int k = 0; k < NOUT; ++k) gv[k] += h * w2[j * NOUT + k];
    }
#pragma unroll
    for (int k = 0; k < NOUT; ++k) {
        gv[k] = (float)Sn * gv[k] + b2[k];
        sh_gv[k][b] = gv[k];
    }

    // wsum[k][o] = sum_s w_fcf[s*10+k][o]
    if (b < NOUT * NOUT) {
        const int k = b / NOUT, o = b % NOUT;
        float w = 0.f;
        for (int s = 0; s < Sn; ++s) w += wf[(s * NOUT + k) * NOUT + o];
        sh_wsum[b] = w;
    }
    __syncthreads();

    // lse[k] = logsumexp over batch (axis 0 of g). 10 k's x 16 partials x 16 vals.
    if (b < NOUT * 16) {
        const int k = b >> 4, part = b & 15;
        float m0 = sh_gv[k][part * 16];
        for (int i = 1; i < 16; ++i) m0 = fmaxf(m0, sh_gv[k][part * 16 + i]);
        sh_part[k][part] = m0;
    }
    __syncthreads();
    if (b < NOUT) {
        float m0 = sh_part[b][0];
        for (int i = 1; i < 16; ++i) m0 = fmaxf(m0, sh_part[b][i]);
        sh_max[b] = m0;
    }
    __syncthreads();
    if (b < NOUT * 16) {
        const int k = b >> 4, part = b & 15;
        const float m0 = sh_max[k];
        float sacc = 0.f;
        for (int i = 0; i < 16; ++i) sacc += expf(sh_gv[k][part * 16 + i] - m0);
        sh_part[k][part] = sacc;
    }
    __syncthreads();
    if (b < NOUT) {
        float sacc = 0.f;
        for (int i = 0; i < 16; ++i) sacc += sh_part[b][i];
        sh_lse[b] = sh_max[b] + logf(sacc);
    }
    __syncthreads();

    // logits[o] = bf[o] + sum_k (gv[k]-lse[k]) * wsum[k][o]; out = softmax
    float lg[NOUT];
#pragma unroll
    for (int k = 0; k < NOUT; ++k) lg[k] = gv[k] - sh_lse[k];
    float logits[NOUT];
#pragma unroll
    for (int o = 0; o < NOUT; ++o) {
        float a = bf[o];
#pragma unroll
        for (int k = 0; k < NOUT; ++k) a += lg[k] * sh_wsum[k * NOUT + o];
        logits[o] = a;
    }
    float mxl = logits[0];
#pragma unroll
    for (int o = 1; o < NOUT; ++o) mxl = fmaxf(mxl, logits[o]);
    float ssum = 0.f;
#pragma unroll
    for (int o = 0; o < NOUT; ++o) { logits[o] = expf(logits[o] - mxl); ssum += logits[o]; }
#pragma unroll
    for (int o = 0; o < NOUT; ++o) out[b * NOUT + o] = logits[o] / ssum;
}

extern "C" void kernel_launch(void* const* d_in, const int* in_sizes, int n_in,
                              void* d_out, int out_size, void* d_ws, size_t ws_size,
                              hipStream_t stream) {
    const float* x   = (const float*)d_in[0];
    const float* u   = (const float*)d_in[1];
    const float* z   = (const float*)d_in[2];
    const float* mg  = (const float*)d_in[3];
    const float* w1  = (const float*)d_in[4];
    const float* b1  = (const float*)d_in[5];
    const float* w2  = (const float*)d_in[6];
    const float* b2  = (const float*)d_in[7];
    const float* wf  = (const float*)d_in[8];
    const float* bf  = (const float*)d_in[9];
    float* out = (float*)d_out;

    float* samples = (float*)d_ws;                    // S*B*5 = 25600 floats
    float* logprob = samples + Sn * Bn * NFEAT;       // S*B   =  5120 floats

    hipLaunchKernelGGL(k_sample, dim3(Sn), dim3(Bn), 0, stream,
                       x, u, z, mg, samples, logprob);
    hipLaunchKernelGGL(k_head, dim3(1), dim3(Bn), 0, stream,
                       samples, logprob, w1, b1, w2, b2, wf, bf, out);
}